// Round 7
// baseline (121.120 us; speedup 1.0000x reference)
//
#include <hip/hip_runtime.h>
#include <hip/hip_bf16.h>

// Problem constants
#define B_SZ   16
#define V_IN   1024
#define V_OUT  4096
#define C_IN   128
#define C_OUT  256
#define K_NB   18
#define NNZ    16384
#define K_GEMM (K_NB * C_IN)   // 2304
#define BK     64
#define NKT    (K_GEMM / BK)   // 36

typedef __attribute__((ext_vector_type(8))) short bf16x8;   // 8 bf16 = 4 VGPRs
typedef __attribute__((ext_vector_type(4))) float f32x4;

#define GLOAD16(src, dst) __builtin_amdgcn_global_load_lds( \
    (const __attribute__((address_space(1))) unsigned int*)(src), \
    (__attribute__((address_space(3))) unsigned int*)(dst), 16, 0, 0)

#define MFMA16(a_, b_, c_) __builtin_amdgcn_mfma_f32_16x16x32_bf16((a_), (b_), (c_), 0, 0, 0)

// ---------------- fused CSR build: hist + scan + fill in one block ----------------
__global__ __launch_bounds__(1024) void csr_kernel(const int* __restrict__ rows,
                                                   int* __restrict__ offsets,
                                                   int* __restrict__ perm) {
    __shared__ int cnt[V_OUT];     // histogram, then cursor
    __shared__ int wsum[16];
    const int t = threadIdx.x;
    const int lane = t & 63, wid = t >> 6;
#pragma unroll
    for (int i = t; i < V_OUT; i += 1024) cnt[i] = 0;
    __syncthreads();
#pragma unroll
    for (int n = t; n < NNZ; n += 1024) atomicAdd(&cnt[rows[n]], 1);
    __syncthreads();
    const int base4 = t * 4;
    int c0 = cnt[base4], c1 = cnt[base4 + 1], c2 = cnt[base4 + 2], c3 = cnt[base4 + 3];
    int tot = c0 + c1 + c2 + c3;
    int v = tot;
#pragma unroll
    for (int d = 1; d < 64; d <<= 1) {
        int u = __shfl_up(v, d);
        if (lane >= d) v += u;
    }
    if (lane == 63) wsum[wid] = v;
    __syncthreads();
    int wbase = 0;
#pragma unroll
    for (int w = 0; w < 16; ++w) wbase += (w < wid) ? wsum[w] : 0;
    int incl = wbase + v;
    int excl = incl - tot;
    offsets[base4]     = excl;
    offsets[base4 + 1] = excl + c0;
    offsets[base4 + 2] = excl + c0 + c1;
    offsets[base4 + 3] = excl + c0 + c1 + c2;
    if (t == 1023) offsets[V_OUT] = incl;
    __syncthreads();   // everyone done reading cnt as histogram
    cnt[base4]     = excl;
    cnt[base4 + 1] = excl + c0;
    cnt[base4 + 2] = excl + c0 + c1;
    cnt[base4 + 3] = excl + c0 + c1 + c2;
    __syncthreads();
#pragma unroll
    for (int n = t; n < NNZ; n += 1024) {
        int pos = atomicAdd(&cnt[rows[n]], 1);
        perm[pos] = n;
    }
}

// ---------------- pooling: block = out-row, threads = (batch 16) x (c4 32), float4 loads ----------------
__global__ __launch_bounds__(512) void pool_kernel(
    const float* __restrict__ x, const float* __restrict__ vals,
    const int* __restrict__ cols, const int* __restrict__ offsets,
    const int* __restrict__ perm, __hip_bfloat16* __restrict__ pool) {
    int r = blockIdx.x;
    int t = threadIdx.x;
    int b = t >> 5, c4 = t & 31;
    int j0 = offsets[r], j1 = offsets[r + 1];
    const float4* xb = (const float4*)x + (size_t)b * (V_IN * 32);
    float4 acc = {0.f, 0.f, 0.f, 0.f};
    for (int j = j0; j < j1; ++j) {
        int n = perm[j];
        float v = vals[n];
        float4 xv = xb[cols[n] * 32 + c4];
        acc.x += v * xv.x; acc.y += v * xv.y; acc.z += v * xv.z; acc.w += v * xv.w;
    }
    ushort4 o;
    o.x = __builtin_bit_cast(unsigned short, __float2bfloat16(acc.x));
    o.y = __builtin_bit_cast(unsigned short, __float2bfloat16(acc.y));
    o.z = __builtin_bit_cast(unsigned short, __float2bfloat16(acc.z));
    o.w = __builtin_bit_cast(unsigned short, __float2bfloat16(acc.w));
    ((ushort4*)pool)[((size_t)b * V_OUT + r) * 32 + c4] = o;
}

// ---------------- combined weight (pre-swizzled per-K-tile fragment image) + bias ----------------
__global__ void wcomb_kernel(const float* __restrict__ W1, const float* __restrict__ Wd3,
                             const float* __restrict__ W2d3, const float* __restrict__ Wf,
                             const float* __restrict__ b1, const float* __restrict__ bd3,
                             const float* __restrict__ b2d3, const float* __restrict__ bf,
                             __hip_bfloat16* __restrict__ wTs, float* __restrict__ bias) {
    int idx = blockIdx.x * blockDim.x + threadIdx.x;
    if (idx >= NKT * 16384) {
        int c = idx - NKT * 16384;
        if (c < C_OUT) {
            float v = b1[c];
            if (c < 128)      v += bf[c];
            else if (c < 192) v += b2d3[c - 128];
            else              v += bd3[c - 192];
            bias[c] = v;
        }
        return;
    }
    int kt = idx >> 14;
    int c  = (idx >> 3) & 2047;
    int e  = idx & 7;
    int nrow  = c >> 3;
    int kslot = (c & 7) << 4;
    int kb = kslot ^ ((nrow & 7) << 4);
    int r  = kt * 64 + (kb >> 1) + e;    // global k, 0..2303
    int col = nrow;
    float v;
    if (col < 128)      v = Wf[r * 128 + col];
    else if (col < 192) v = (r < 1536) ? W2d3[r * 64 + (col - 128)] : 0.f;
    else                v = (r < 768)  ? Wd3[r * 64 + (col - 192)]  : 0.f;
    if (r < 128) v += W1[r * 256 + col];
    wTs[idx] = __float2bfloat16(v);
}

// ---------------- gathered GEMM: 128x256 block, 8 waves (64x64), 2 blocks/CU,
// A in 3-slot LDS (staged 2 ahead), B direct from global fragment image ----------------
__global__ __launch_bounds__(512, 4) void gemm_kernel(
    const __hip_bfloat16* __restrict__ pool,    // [16][4096][128] bf16
    const __hip_bfloat16* __restrict__ wTs,     // [36][16384] bf16, fragment-image K-tiles
    const float* __restrict__ bias,             // [256]
    const int* __restrict__ spiral,             // [4096][18]
    float* __restrict__ out)                    // [16][4096][256] f32
{
    // LDS: A slots @0,16384,32768 ; u16 spiral cache @49152 (4608 B) -> 53760 B total
    __shared__ __align__(16) char smem[53760];
    unsigned short* spl = (unsigned short*)(smem + 49152);

    const int tid  = threadIdx.x;
    const int lane = tid & 63;
    const int wid  = tid >> 6;          // 0..7
    const int q    = wid & 3;           // balanced-skip column group
    const int wmL  = (wid >> 2) << 6;   // 0 / 64 row band within 128-row tile

    const int bid = blockIdx.x;
    const int bm  = ((bid & 7) << 6) + (bid >> 3);   // bijective XCD swizzle (512 = 8*64)
    const int b   = bm >> 5;                          // batch 0..15
    const int v0  = (bm & 31) << 7;                   // 128-row tile origin within batch

    // cache this block's spiral rows as u16: 128 rows x 18
    for (int i = tid; i < 128 * K_NB; i += 512)
        spl[i] = (unsigned short)spiral[(v0 + i / K_NB) * K_NB + (i % K_NB)];
    asm volatile("s_waitcnt vmcnt(0) lgkmcnt(0)" ::: "memory");
    __builtin_amdgcn_s_barrier();

    const char* poolBytes = (const char*)(pool + (size_t)b * V_OUT * C_IN);
    const char* wTsBytes  = (const char*)wTs;
    // inverse-swizzled source column byte (row&7 == (tid>>3)&7 for both 512-chunks)
    const int sb = ((tid & 7) << 4) ^ (((tid >> 3) & 7) << 4);

    auto stageA = [&](int kt, int slot) {          // 2 gloads per thread
        const int j   = kt >> 1;
        const int c0b = (kt & 1) << 7;
        char* dst = smem + slot * 16384;
#pragma unroll
        for (int ch = 0; ch < 2; ++ch) {
            int flat = (ch << 9) + tid;            // 0..1023 = 128 rows x 8 slots
            int sidx = spl[(flat >> 3) * K_NB + j];
            GLOAD16(poolBytes + ((size_t)sidx << 8) + (c0b + sb), dst + (flat << 4));
        }
    };

    // per-lane fragment-read constants
    const int l15   = lane & 15;
    const int swm   = (lane & 7) << 4;
    const int klane = (lane >> 4) << 4;
    const int kk0   = klane ^ swm;
    const int kk1   = (64 + klane) ^ swm;
    const int aBase = (wmL + l15) << 7;
    const int bO0 = (((2 * q)     << 4) + l15) << 7;   // full-K col tile
    const int bO1 = (((2 * q + 1) << 4) + l15) << 7;   // full-K col tile
    const int bO2 = (((8 + q)     << 4) + l15) << 7;   // mid (kt<24)
    const int bO3 = (((12 + q)    << 4) + l15) << 7;   // short (kt<12)

    f32x4 acc[4][4] = {};

    stageA(0, 0);
    stageA(1, 1);

    int sl = 0;
    for (int kt = 0; kt < NKT; ++kt) {
        if (kt + 1 < NKT) asm volatile("s_waitcnt vmcnt(2)" ::: "memory");  // A(kt) landed
        else              asm volatile("s_waitcnt vmcnt(0)" ::: "memory");
        __builtin_amdgcn_s_barrier();
        __builtin_amdgcn_sched_barrier(0);

        const char* As  = smem + sl * 16384;
        const char* wKt = wTsBytes + ((size_t)kt << 15);
        const bool doMid = kt < 24, doShort = kt < 12;
        bf16x8 a[4], b0, b1, b2, b3;

        // ================= ks = 0 =================
        b0 = *(const bf16x8*)(wKt + bO0 + kk0);
        b1 = *(const bf16x8*)(wKt + bO1 + kk0);
        if (doMid)   b2 = *(const bf16x8*)(wKt + bO2 + kk0);
        if (doShort) b3 = *(const bf16x8*)(wKt + bO3 + kk0);
#pragma unroll
        for (int mi = 0; mi < 4; ++mi)
            a[mi] = *(const bf16x8*)(As + aBase + (mi << 11) + kk0);
        __builtin_amdgcn_s_setprio(1);
#pragma unroll
        for (int mi = 0; mi < 4; ++mi) {
            acc[mi][0] = MFMA16(a[mi], b0, acc[mi][0]);
            acc[mi][1] = MFMA16(a[mi], b1, acc[mi][1]);
        }
        if (doMid) {
#pragma unroll
            for (int mi = 0; mi < 4; ++mi) acc[mi][2] = MFMA16(a[mi], b2, acc[mi][2]);
        }
        if (doShort) {
#pragma unroll
            for (int mi = 0; mi < 4; ++mi) acc[mi][3] = MFMA16(a[mi], b3, acc[mi][3]);
        }
        __builtin_amdgcn_s_setprio(0);

        // ================= ks = 1 =================
        b0 = *(const bf16x8*)(wKt + bO0 + kk1);
        b1 = *(const bf16x8*)(wKt + bO1 + kk1);
        if (doMid)   b2 = *(const bf16x8*)(wKt + bO2 + kk1);
        if (doShort) b3 = *(const bf16x8*)(wKt + bO3 + kk1);
#pragma unroll
        for (int mi = 0; mi < 4; ++mi)
            a[mi] = *(const bf16x8*)(As + aBase + (mi << 11) + kk1);
        __builtin_amdgcn_sched_barrier(0);
        // stage A(kt+2) LAST so MFMA's B-wait is vmcnt(2), keeping these in flight
        if (kt + 2 < NKT) {
            int st = sl + 2; if (st >= 3) st -= 3;
            stageA(kt + 2, st);
        }
        __builtin_amdgcn_sched_barrier(0);
        __builtin_amdgcn_s_setprio(1);
#pragma unroll
        for (int mi = 0; mi < 4; ++mi) {
            acc[mi][0] = MFMA16(a[mi], b0, acc[mi][0]);
            acc[mi][1] = MFMA16(a[mi], b1, acc[mi][1]);
        }
        if (doMid) {
#pragma unroll
            for (int mi = 0; mi < 4; ++mi) acc[mi][2] = MFMA16(a[mi], b2, acc[mi][2]);
        }
        if (doShort) {
#pragma unroll
            for (int mi = 0; mi < 4; ++mi) acc[mi][3] = MFMA16(a[mi], b3, acc[mi][3]);
        }
        __builtin_amdgcn_s_setprio(0);

        sl += 1; if (sl >= 3) sl -= 3;
    }

    // epilogue: +bias, relu, store f32
    const int nt[4] = {2 * q, 2 * q + 1, 8 + q, 12 + q};
#pragma unroll
    for (int ni = 0; ni < 4; ++ni) {
        int col = (nt[ni] << 4) + l15;
        float bz = bias[col];
#pragma unroll
        for (int mi = 0; mi < 4; ++mi) {
            int row0 = v0 + wmL + mi * 16 + ((lane >> 4) << 2);
#pragma unroll
            for (int r4 = 0; r4 < 4; ++r4) {
                float v = acc[mi][ni][r4] + bz;
                out[((size_t)(b * V_OUT + row0 + r4)) * C_OUT + col] = v > 0.f ? v : 0.f;
            }
        }
    }
}

extern "C" void kernel_launch(void* const* d_in, const int* in_sizes, int n_in,
                              void* d_out, int out_size, void* d_ws, size_t ws_size,
                              hipStream_t stream) {
    const float* x     = (const float*)d_in[0];
    const float* vals  = (const float*)d_in[1];
    const float* W1    = (const float*)d_in[2];
    const float* b1    = (const float*)d_in[3];
    const float* Wd3   = (const float*)d_in[4];
    const float* bd3   = (const float*)d_in[5];
    const float* W2d3  = (const float*)d_in[6];
    const float* b2d3  = (const float*)d_in[7];
    const float* Wf    = (const float*)d_in[8];
    const float* bf    = (const float*)d_in[9];
    const int*   rows  = (const int*)d_in[10];
    const int*   cols  = (const int*)d_in[11];
    const int*   spiral= (const int*)d_in[12];
    float* out = (float*)d_out;

    // workspace layout
    char* ws = (char*)d_ws;
    __hip_bfloat16* pool = (__hip_bfloat16*)ws;                              // 16,777,216 B
    __hip_bfloat16* wTs  = (__hip_bfloat16*)(ws + 16777216);                 //  1,179,648 B
    float* bias          = (float*)(ws + 16777216 + 1179648);                //      1,024 B
    int*   offsets       = (int*)(ws + 16777216 + 1179648 + 1024);           // V_OUT+1 ints
    int*   perm          = offsets + V_OUT + 4;

    csr_kernel<<<1, 1024, 0, stream>>>(rows, offsets, perm);
    pool_kernel<<<V_OUT, 512, 0, stream>>>(x, vals, cols, offsets, perm, pool);
    wcomb_kernel<<<(NKT * 16384 + C_OUT + 255) / 256, 256, 0, stream>>>(
        W1, Wd3, W2d3, Wf, b1, bd3, b2d3, bf, wTs, bias);
    gemm_kernel<<<512, 512, 0, stream>>>(pool, wTs, bias, spiral, out);
}